// Round 6
// baseline (145.397 us; speedup 1.0000x reference)
//
#include <hip/hip_runtime.h>
#include <stdint.h>

// MaxSimLoss: anchor [256,64,128] f32, pos/neg [256,512,128] f32 -> scalar f32.
// Memory/latency-bound (142 MB, HBM floor ~23 us). Barrier-free main loop,
// MFMA fragments loaded straight from global in fragment layout, norms
// in-register. R5 post-mortem: 8-wave blocks under launch_bounds(512,4)
// spilled (WRITE_SIZE 246 MB) -> 134 us. R6: keep the proven 108-VGPR 4-wave
// block; double the GRID instead (s-split x2 -> 1024 blocks = 16 waves/CU).
// max_s commutes with the positive invA scale, so blocks emit per-t partial
// maxima; a tiny combine kernel finishes max/mean/hinge.

#define MARGIN_F 0.1f

typedef __attribute__((ext_vector_type(8))) short short8;   // 8 bf16
typedef __attribute__((ext_vector_type(4))) float floatx4;  // 4 f32 acc

// f32 -> bf16 round-to-nearest-even (inputs finite).
__device__ __forceinline__ unsigned short f2bf(float f) {
  union { float f; uint32_t u; } x; x.f = f;
  uint32_t u = x.u;
  return (unsigned short)((u + 0x7FFFu + ((u >> 16) & 1u)) >> 16);
}

__device__ __forceinline__ short8 pack8(float4 a, float4 b) {
  short8 r;
  r[0] = (short)f2bf(a.x); r[1] = (short)f2bf(a.y);
  r[2] = (short)f2bf(a.z); r[3] = (short)f2bf(a.w);
  r[4] = (short)f2bf(b.x); r[5] = (short)f2bf(b.y);
  r[6] = (short)f2bf(b.z); r[7] = (short)f2bf(b.w);
  return r;
}

__device__ __forceinline__ float sq4(float4 a) {
  return a.x * a.x + a.y * a.y + a.z * a.z + a.w * a.w;
}

// One block per (batch, side, s-half); 4 waves partition the 256-row s-half
// (64 rows each, 4 chunks of 16). Fragment pattern (verified R2/R3): lane
// holds row (lane&15), elements (lane>>4)*8 + k*32..+8 per k-slice; identical
// for A and B -> D = A.B^T with row(t) = (lane>>4)*4 + j, col(s) = lane&15.
__global__ __launch_bounds__(256, 4) void maxsim_kernel(
    const float* __restrict__ anchor, const float* __restrict__ pos,
    const float* __restrict__ neg, float* __restrict__ part) {
  __shared__ float sInvA[64];
  __shared__ float sPart[4][64];

  int bs2 = blockIdx.x;     // 0..1023
  int sh = bs2 & 1;         // s-half
  int bs = bs2 >> 1;        // (batch, side)
  int b = bs >> 1;
  int side = bs & 1;
  const float* base =
      (side ? neg : pos) + (size_t)b * 512 * 128 + (size_t)sh * 256 * 128;
  const float* abase = anchor + (size_t)b * 64 * 128;

  int tid = threadIdx.x;
  int lane = tid & 63;
  int wid = tid >> 6;  // 0..3
  int r = lane & 15;   // fragment row within subtile / accumulator col
  int g = lane >> 4;   // k-group (elements g*8 + k*32)

  const float* sbase = base + (size_t)wid * 64 * 128;

  // Issue chunk-0 s-loads FIRST so their latency hides under the anchor phase.
  float4 buf[2][8];  // fully unrolled chunk loop -> static indexing (rule #20)
  {
    const float* p = sbase + (size_t)r * 128 + g * 8;
#pragma unroll
    for (int k = 0; k < 4; ++k) {
      buf[0][2 * k] = *reinterpret_cast<const float4*>(p + k * 32);
      buf[0][2 * k + 1] = *reinterpret_cast<const float4*>(p + k * 32 + 4);
    }
  }

  // --- A: all 4 t-subtiles into registers, norms in-register. ---
  short8 aF[4][4];
#pragma unroll
  for (int tst = 0; tst < 4; ++tst) {
    const float* arow = abase + (size_t)(tst * 16 + r) * 128 + g * 8;
    float ssa[4];
#pragma unroll
    for (int k = 0; k < 4; ++k) {
      float4 v0 = *reinterpret_cast<const float4*>(arow + k * 32);
      float4 v1 = *reinterpret_cast<const float4*>(arow + k * 32 + 4);
      ssa[k] = sq4(v0) + sq4(v1);
      aF[tst][k] = pack8(v0, v1);
    }
    float ss = (ssa[0] + ssa[1]) + (ssa[2] + ssa[3]);  // tree, short chain
    ss += __shfl_xor(ss, 16);
    ss += __shfl_xor(ss, 32);
    if (g == 0) sInvA[tst * 16 + r] = 1.0f / fmaxf(sqrtf(ss), 1e-12f);
  }
  __syncthreads();  // sInvA ready; last sync until epilogue

  float rmax[4][4];
#pragma unroll
  for (int tst = 0; tst < 4; ++tst)
#pragma unroll
    for (int j = 0; j < 4; ++j) rmax[tst][j] = -1e30f;

#pragma unroll
  for (int i = 0; i < 4; ++i) {
    int cur = i & 1;
    if (i < 3) {
      const float* p = sbase + (size_t)((i + 1) * 16 + r) * 128 + g * 8;
#pragma unroll
      for (int k = 0; k < 4; ++k) {
        buf[cur ^ 1][2 * k] = *reinterpret_cast<const float4*>(p + k * 32);
        buf[cur ^ 1][2 * k + 1] =
            *reinterpret_cast<const float4*>(p + k * 32 + 4);
      }
    }
    // Row norm for this lane's loaded row (s = sh*256 + wid*64 + i*16 + r).
    float ss = ((sq4(buf[cur][0]) + sq4(buf[cur][1])) +
                (sq4(buf[cur][2]) + sq4(buf[cur][3]))) +
               ((sq4(buf[cur][4]) + sq4(buf[cur][5])) +
                (sq4(buf[cur][6]) + sq4(buf[cur][7])));
    ss += __shfl_xor(ss, 16);
    ss += __shfl_xor(ss, 32);
    float invb = 1.0f / fmaxf(sqrtf(ss), 1e-12f);

    short8 bF[4];
#pragma unroll
    for (int k = 0; k < 4; ++k)
      bF[k] = pack8(buf[cur][2 * k], buf[cur][2 * k + 1]);

    floatx4 acc[4] = {{0.f, 0.f, 0.f, 0.f},
                      {0.f, 0.f, 0.f, 0.f},
                      {0.f, 0.f, 0.f, 0.f},
                      {0.f, 0.f, 0.f, 0.f}};
#pragma unroll
    for (int k = 0; k < 4; ++k)
#pragma unroll
      for (int tst = 0; tst < 4; ++tst)
        acc[tst] = __builtin_amdgcn_mfma_f32_16x16x32_bf16(aF[tst][k], bF[k],
                                                           acc[tst], 0, 0, 0);
    // acc[tst][j]: row t = tst*16 + g*4 + j, col s-rel = lane&15.
    // invb for col r is this lane's own invb (it loaded row i*16 + r).
#pragma unroll
    for (int tst = 0; tst < 4; ++tst)
#pragma unroll
      for (int j = 0; j < 4; ++j)
        rmax[tst][j] = fmaxf(rmax[tst][j], acc[tst][j] * invb);
  }

  // Butterfly-max over cols (lane bits 0-3) -> per-t max over wave's s-range.
#pragma unroll
  for (int tst = 0; tst < 4; ++tst)
#pragma unroll
    for (int j = 0; j < 4; ++j) {
      float m = rmax[tst][j];
      m = fmaxf(m, __shfl_xor(m, 1));
      m = fmaxf(m, __shfl_xor(m, 2));
      m = fmaxf(m, __shfl_xor(m, 4));
      m = fmaxf(m, __shfl_xor(m, 8));
      rmax[tst][j] = m;  // t = tst*16 + g*4 + j, uniform over lane bits 0-3
    }
  if (r == 0) {
#pragma unroll
    for (int tst = 0; tst < 4; ++tst)
#pragma unroll
      for (int j = 0; j < 4; ++j)
        sPart[wid][tst * 16 + g * 4 + j] = rmax[tst][j];
  }
  __syncthreads();
  // Per-t partial max over this block's 256 s-rows, scaled by invA (positive,
  // commutes with the cross-block max done in combine_kernel).
  if (tid < 64) {
    float m = fmaxf(fmaxf(sPart[0][tid], sPart[1][tid]),
                    fmaxf(sPart[2][tid], sPart[3][tid]));
    part[(size_t)bs2 * 64 + tid] = m * sInvA[tid];
  }
}

// part[bs*128 + sh*64 + t] -> max over sh, mean over t, hinge, mean over b.
// One block, 1024 threads: thread pair (bit0) splits t; bit1 is the side.
__global__ void combine_kernel(const float* __restrict__ part,
                               float* __restrict__ out) {
  int tid = threadIdx.x;  // 0..1023
  int bs = tid >> 1;      // 0..511 = batch*2 + side
  int tq = tid & 1;
  const float* p0 = part + (size_t)bs * 128 + tq * 32;
  float sum = 0.f;
#pragma unroll
  for (int i = 0; i < 32; ++i) sum += fmaxf(p0[i], p0[64 + i]);
  sum += __shfl_xor(sum, 1);  // total over all 64 t
  float score = sum * (1.0f / 64.0f);
  float other = __shfl_xor(score, 2);  // swap side (bit1 of tid, intra-wave)
  float h = fmaxf(MARGIN_F + other - score, 0.0f);  // valid where side==0
  h = ((tid & 3) == 0) ? h : 0.f;  // one lane per batch contributes
  h += __shfl_xor(h, 1);
  h += __shfl_xor(h, 2);
  h += __shfl_xor(h, 4);
  h += __shfl_xor(h, 8);
  h += __shfl_xor(h, 16);
  h += __shfl_xor(h, 32);
  __shared__ float sw[16];
  if ((tid & 63) == 0) sw[tid >> 6] = h;
  __syncthreads();
  if (tid < 16) {
    float v = sw[tid];
    v += __shfl_xor(v, 1);
    v += __shfl_xor(v, 2);
    v += __shfl_xor(v, 4);
    v += __shfl_xor(v, 8);
    if (tid == 0) out[0] = v * (1.0f / 256.0f);
  }
}

extern "C" void kernel_launch(void* const* d_in, const int* in_sizes, int n_in,
                              void* d_out, int out_size, void* d_ws,
                              size_t ws_size, hipStream_t stream) {
  const float* anchor = (const float*)d_in[0];
  const float* pos = (const float*)d_in[1];
  const float* neg = (const float*)d_in[2];
  float* part = (float*)d_ws;  // 1024 blocks x 64 floats = 256 KB scratch
  maxsim_kernel<<<dim3(1024), dim3(256), 0, stream>>>(anchor, pos, neg, part);
  combine_kernel<<<dim3(1), dim3(1024), 0, stream>>>(part, (float*)d_out);
}

// Round 7
// 50.917 us; speedup vs baseline: 2.8555x; 2.8555x over previous
//
#include <hip/hip_runtime.h>
#include <stdint.h>

// MaxSimLoss: anchor [256,64,128] f32, pos/neg [256,512,128] f32 -> scalar f32.
// Memory/latency-bound (142 MB, HBM floor ~23 us). Barrier-free main loop,
// MFMA fragments loaded straight from global in fragment layout, norms
// in-register. R6 post-mortem: launch_bounds(256,4) split the unified RF
// 64 arch + 64 acc -> spills (WRITE 257 MB). At 108 VGPR the HW already
// allows 4 waves/SIMD; R3 was merely GRID-limited (8 waves/CU). R7: keep the
// 1024-block s-split grid, restore launch_bounds(256,2) -> 108 VGPR, no
// spill, 16 waves/CU from the grid alone.

#define MARGIN_F 0.1f

typedef __attribute__((ext_vector_type(8))) short short8;   // 8 bf16
typedef __attribute__((ext_vector_type(4))) float floatx4;  // 4 f32 acc

// f32 -> bf16 round-to-nearest-even (inputs finite).
__device__ __forceinline__ unsigned short f2bf(float f) {
  union { float f; uint32_t u; } x; x.f = f;
  uint32_t u = x.u;
  return (unsigned short)((u + 0x7FFFu + ((u >> 16) & 1u)) >> 16);
}

__device__ __forceinline__ short8 pack8(float4 a, float4 b) {
  short8 r;
  r[0] = (short)f2bf(a.x); r[1] = (short)f2bf(a.y);
  r[2] = (short)f2bf(a.z); r[3] = (short)f2bf(a.w);
  r[4] = (short)f2bf(b.x); r[5] = (short)f2bf(b.y);
  r[6] = (short)f2bf(b.z); r[7] = (short)f2bf(b.w);
  return r;
}

__device__ __forceinline__ float sq4(float4 a) {
  return a.x * a.x + a.y * a.y + a.z * a.z + a.w * a.w;
}

// One block per (batch, side, s-half); 4 waves partition the 256-row s-half
// (64 rows each, 4 chunks of 16). Fragment pattern (verified R2/R3): lane
// holds row (lane&15), elements (lane>>4)*8 + k*32..+8 per k-slice; identical
// for A and B -> D = A.B^T with row(t) = (lane>>4)*4 + j, col(s) = lane&15.
__global__ __launch_bounds__(256, 2) void maxsim_kernel(
    const float* __restrict__ anchor, const float* __restrict__ pos,
    const float* __restrict__ neg, float* __restrict__ part) {
  __shared__ float sInvA[64];
  __shared__ float sPart[4][64];

  int bs2 = blockIdx.x;     // 0..1023
  int sh = bs2 & 1;         // s-half
  int bs = bs2 >> 1;        // (batch, side)
  int b = bs >> 1;
  int side = bs & 1;
  const float* base =
      (side ? neg : pos) + (size_t)b * 512 * 128 + (size_t)sh * 256 * 128;
  const float* abase = anchor + (size_t)b * 64 * 128;

  int tid = threadIdx.x;
  int lane = tid & 63;
  int wid = tid >> 6;  // 0..3
  int r = lane & 15;   // fragment row within subtile / accumulator col
  int g = lane >> 4;   // k-group (elements g*8 + k*32)

  const float* sbase = base + (size_t)wid * 64 * 128;

  // Issue chunk-0 s-loads FIRST so their latency hides under the anchor phase.
  float4 buf[2][8];  // fully unrolled chunk loop -> static indexing (rule #20)
  {
    const float* p = sbase + (size_t)r * 128 + g * 8;
#pragma unroll
    for (int k = 0; k < 4; ++k) {
      buf[0][2 * k] = *reinterpret_cast<const float4*>(p + k * 32);
      buf[0][2 * k + 1] = *reinterpret_cast<const float4*>(p + k * 32 + 4);
    }
  }

  // --- A: all 4 t-subtiles into registers, norms in-register. ---
  short8 aF[4][4];
#pragma unroll
  for (int tst = 0; tst < 4; ++tst) {
    const float* arow = abase + (size_t)(tst * 16 + r) * 128 + g * 8;
    float ssa[4];
#pragma unroll
    for (int k = 0; k < 4; ++k) {
      float4 v0 = *reinterpret_cast<const float4*>(arow + k * 32);
      float4 v1 = *reinterpret_cast<const float4*>(arow + k * 32 + 4);
      ssa[k] = sq4(v0) + sq4(v1);
      aF[tst][k] = pack8(v0, v1);
    }
    float ss = (ssa[0] + ssa[1]) + (ssa[2] + ssa[3]);  // tree, short chain
    ss += __shfl_xor(ss, 16);
    ss += __shfl_xor(ss, 32);
    if (g == 0) sInvA[tst * 16 + r] = 1.0f / fmaxf(sqrtf(ss), 1e-12f);
  }
  __syncthreads();  // sInvA ready; last sync until epilogue

  float rmax[4][4];
#pragma unroll
  for (int tst = 0; tst < 4; ++tst)
#pragma unroll
    for (int j = 0; j < 4; ++j) rmax[tst][j] = -1e30f;

#pragma unroll
  for (int i = 0; i < 4; ++i) {
    int cur = i & 1;
    if (i < 3) {
      const float* p = sbase + (size_t)((i + 1) * 16 + r) * 128 + g * 8;
#pragma unroll
      for (int k = 0; k < 4; ++k) {
        buf[cur ^ 1][2 * k] = *reinterpret_cast<const float4*>(p + k * 32);
        buf[cur ^ 1][2 * k + 1] =
            *reinterpret_cast<const float4*>(p + k * 32 + 4);
      }
    }
    // Row norm for this lane's loaded row (s = sh*256 + wid*64 + i*16 + r).
    float ss = ((sq4(buf[cur][0]) + sq4(buf[cur][1])) +
                (sq4(buf[cur][2]) + sq4(buf[cur][3]))) +
               ((sq4(buf[cur][4]) + sq4(buf[cur][5])) +
                (sq4(buf[cur][6]) + sq4(buf[cur][7])));
    ss += __shfl_xor(ss, 16);
    ss += __shfl_xor(ss, 32);
    float invb = 1.0f / fmaxf(sqrtf(ss), 1e-12f);

    short8 bF[4];
#pragma unroll
    for (int k = 0; k < 4; ++k)
      bF[k] = pack8(buf[cur][2 * k], buf[cur][2 * k + 1]);

    floatx4 acc[4] = {{0.f, 0.f, 0.f, 0.f},
                      {0.f, 0.f, 0.f, 0.f},
                      {0.f, 0.f, 0.f, 0.f},
                      {0.f, 0.f, 0.f, 0.f}};
#pragma unroll
    for (int k = 0; k < 4; ++k)
#pragma unroll
      for (int tst = 0; tst < 4; ++tst)
        acc[tst] = __builtin_amdgcn_mfma_f32_16x16x32_bf16(aF[tst][k], bF[k],
                                                           acc[tst], 0, 0, 0);
    // acc[tst][j]: row t = tst*16 + g*4 + j, col s-rel = lane&15.
    // invb for col r is this lane's own invb (it loaded row i*16 + r).
#pragma unroll
    for (int tst = 0; tst < 4; ++tst)
#pragma unroll
      for (int j = 0; j < 4; ++j)
        rmax[tst][j] = fmaxf(rmax[tst][j], acc[tst][j] * invb);
  }

  // Butterfly-max over cols (lane bits 0-3) -> per-t max over wave's s-range.
#pragma unroll
  for (int tst = 0; tst < 4; ++tst)
#pragma unroll
    for (int j = 0; j < 4; ++j) {
      float m = rmax[tst][j];
      m = fmaxf(m, __shfl_xor(m, 1));
      m = fmaxf(m, __shfl_xor(m, 2));
      m = fmaxf(m, __shfl_xor(m, 4));
      m = fmaxf(m, __shfl_xor(m, 8));
      rmax[tst][j] = m;  // t = tst*16 + g*4 + j, uniform over lane bits 0-3
    }
  if (r == 0) {
#pragma unroll
    for (int tst = 0; tst < 4; ++tst)
#pragma unroll
      for (int j = 0; j < 4; ++j)
        sPart[wid][tst * 16 + g * 4 + j] = rmax[tst][j];
  }
  __syncthreads();
  // Per-t partial max over this block's 256 s-rows, scaled by invA (positive,
  // commutes with the cross-block max done in combine_kernel).
  if (tid < 64) {
    float m = fmaxf(fmaxf(sPart[0][tid], sPart[1][tid]),
                    fmaxf(sPart[2][tid], sPart[3][tid]));
    part[(size_t)bs2 * 64 + tid] = m * sInvA[tid];
  }
}

// part[bs*128 + sh*64 + t] -> max over sh, mean over t, hinge, mean over b.
// One block, 1024 threads: thread pair (bit0) splits t; bit1 is the side.
__global__ void combine_kernel(const float* __restrict__ part,
                               float* __restrict__ out) {
  int tid = threadIdx.x;  // 0..1023
  int bs = tid >> 1;      // 0..511 = batch*2 + side
  int tq = tid & 1;
  const float* p0 = part + (size_t)bs * 128 + tq * 32;
  float sum = 0.f;
#pragma unroll
  for (int i = 0; i < 32; ++i) sum += fmaxf(p0[i], p0[64 + i]);
  sum += __shfl_xor(sum, 1);  // total over all 64 t
  float score = sum * (1.0f / 64.0f);
  float other = __shfl_xor(score, 2);  // swap side (bit1 of tid, intra-wave)
  float h = fmaxf(MARGIN_F + other - score, 0.0f);  // valid where side==0
  h = ((tid & 3) == 0) ? h : 0.f;  // one lane per batch contributes
  h += __shfl_xor(h, 1);
  h += __shfl_xor(h, 2);
  h += __shfl_xor(h, 4);
  h += __shfl_xor(h, 8);
  h += __shfl_xor(h, 16);
  h += __shfl_xor(h, 32);
  __shared__ float sw[16];
  if ((tid & 63) == 0) sw[tid >> 6] = h;
  __syncthreads();
  if (tid < 16) {
    float v = sw[tid];
    v += __shfl_xor(v, 1);
    v += __shfl_xor(v, 2);
    v += __shfl_xor(v, 4);
    v += __shfl_xor(v, 8);
    if (tid == 0) out[0] = v * (1.0f / 256.0f);
  }
}

extern "C" void kernel_launch(void* const* d_in, const int* in_sizes, int n_in,
                              void* d_out, int out_size, void* d_ws,
                              size_t ws_size, hipStream_t stream) {
  const float* anchor = (const float*)d_in[0];
  const float* pos = (const float*)d_in[1];
  const float* neg = (const float*)d_in[2];
  float* part = (float*)d_ws;  // 1024 blocks x 64 floats = 256 KB scratch
  maxsim_kernel<<<dim3(1024), dim3(256), 0, stream>>>(anchor, pos, neg, part);
  combine_kernel<<<dim3(1), dim3(1024), 0, stream>>>(part, (float*)d_out);
}

// Round 9
// 43.001 us; speedup vs baseline: 3.3813x; 1.1841x over previous
//
#include <hip/hip_runtime.h>
#include <stdint.h>

// MaxSimLoss: anchor [256,64,128] f32, pos/neg [256,512,128] f32 -> scalar f32.
// Memory/latency-bound (142 MB, HBM floor ~17-23 us). Barrier-free main loop,
// MFMA fragments loaded straight from global in fragment layout, norms
// in-register. R7 post-mortem: spills fixed (WRITE 257MB -> 0.26MB) but bench
// regressed 36.8 -> 50.9 us: the single-block combine (65K scalar loads on one
// CU) is a serial latency tail masking the maxsim grid experiment. R8: same
// maxsim, split the tail into 256-block per-batch hinge + tiny final sum.

#define MARGIN_F 0.1f

typedef __attribute__((ext_vector_type(8))) short short8;   // 8 bf16
typedef __attribute__((ext_vector_type(4))) float floatx4;  // 4 f32 acc

// f32 -> bf16 round-to-nearest-even (inputs finite).
__device__ __forceinline__ unsigned short f2bf(float f) {
  union { float f; uint32_t u; } x; x.f = f;
  uint32_t u = x.u;
  return (unsigned short)((u + 0x7FFFu + ((u >> 16) & 1u)) >> 16);
}

__device__ __forceinline__ short8 pack8(float4 a, float4 b) {
  short8 r;
  r[0] = (short)f2bf(a.x); r[1] = (short)f2bf(a.y);
  r[2] = (short)f2bf(a.z); r[3] = (short)f2bf(a.w);
  r[4] = (short)f2bf(b.x); r[5] = (short)f2bf(b.y);
  r[6] = (short)f2bf(b.z); r[7] = (short)f2bf(b.w);
  return r;
}

__device__ __forceinline__ float sq4(float4 a) {
  return a.x * a.x + a.y * a.y + a.z * a.z + a.w * a.w;
}

// One block per (batch, side, s-half); 4 waves partition the 256-row s-half
// (64 rows each, 4 chunks of 16). Fragment pattern (verified R2/R3): lane
// holds row (lane&15), elements (lane>>4)*8 + k*32..+8 per k-slice; identical
// for A and B -> D = A.B^T with row(t) = (lane>>4)*4 + j, col(s) = lane&15.
__global__ __launch_bounds__(256, 2) void maxsim_kernel(
    const float* __restrict__ anchor, const float* __restrict__ pos,
    const float* __restrict__ neg, float* __restrict__ part) {
  __shared__ float sInvA[64];
  __shared__ float sPart[4][64];

  int bs2 = blockIdx.x;     // 0..1023 = ((b*2+side)*2+sh)
  int sh = bs2 & 1;         // s-half
  int bs = bs2 >> 1;        // (batch, side)
  int b = bs >> 1;
  int side = bs & 1;
  const float* base =
      (side ? neg : pos) + (size_t)b * 512 * 128 + (size_t)sh * 256 * 128;
  const float* abase = anchor + (size_t)b * 64 * 128;

  int tid = threadIdx.x;
  int lane = tid & 63;
  int wid = tid >> 6;  // 0..3
  int r = lane & 15;   // fragment row within subtile / accumulator col
  int g = lane >> 4;   // k-group (elements g*8 + k*32)

  const float* sbase = base + (size_t)wid * 64 * 128;

  // Issue chunk-0 s-loads FIRST so their latency hides under the anchor phase.
  float4 buf[2][8];  // fully unrolled chunk loop -> static indexing (rule #20)
  {
    const float* p = sbase + (size_t)r * 128 + g * 8;
#pragma unroll
    for (int k = 0; k < 4; ++k) {
      buf[0][2 * k] = *reinterpret_cast<const float4*>(p + k * 32);
      buf[0][2 * k + 1] = *reinterpret_cast<const float4*>(p + k * 32 + 4);
    }
  }

  // --- A: all 4 t-subtiles into registers, norms in-register. ---
  short8 aF[4][4];
#pragma unroll
  for (int tst = 0; tst < 4; ++tst) {
    const float* arow = abase + (size_t)(tst * 16 + r) * 128 + g * 8;
    float ssa[4];
#pragma unroll
    for (int k = 0; k < 4; ++k) {
      float4 v0 = *reinterpret_cast<const float4*>(arow + k * 32);
      float4 v1 = *reinterpret_cast<const float4*>(arow + k * 32 + 4);
      ssa[k] = sq4(v0) + sq4(v1);
      aF[tst][k] = pack8(v0, v1);
    }
    float ss = (ssa[0] + ssa[1]) + (ssa[2] + ssa[3]);  // tree, short chain
    ss += __shfl_xor(ss, 16);
    ss += __shfl_xor(ss, 32);
    if (g == 0) sInvA[tst * 16 + r] = 1.0f / fmaxf(sqrtf(ss), 1e-12f);
  }
  __syncthreads();  // sInvA ready; last sync until epilogue

  float rmax[4][4];
#pragma unroll
  for (int tst = 0; tst < 4; ++tst)
#pragma unroll
    for (int j = 0; j < 4; ++j) rmax[tst][j] = -1e30f;

#pragma unroll
  for (int i = 0; i < 4; ++i) {
    int cur = i & 1;
    if (i < 3) {
      const float* p = sbase + (size_t)((i + 1) * 16 + r) * 128 + g * 8;
#pragma unroll
      for (int k = 0; k < 4; ++k) {
        buf[cur ^ 1][2 * k] = *reinterpret_cast<const float4*>(p + k * 32);
        buf[cur ^ 1][2 * k + 1] =
            *reinterpret_cast<const float4*>(p + k * 32 + 4);
      }
    }
    // Row norm for this lane's loaded row (s = sh*256 + wid*64 + i*16 + r).
    float ss = ((sq4(buf[cur][0]) + sq4(buf[cur][1])) +
                (sq4(buf[cur][2]) + sq4(buf[cur][3]))) +
               ((sq4(buf[cur][4]) + sq4(buf[cur][5])) +
                (sq4(buf[cur][6]) + sq4(buf[cur][7])));
    ss += __shfl_xor(ss, 16);
    ss += __shfl_xor(ss, 32);
    float invb = 1.0f / fmaxf(sqrtf(ss), 1e-12f);

    short8 bF[4];
#pragma unroll
    for (int k = 0; k < 4; ++k)
      bF[k] = pack8(buf[cur][2 * k], buf[cur][2 * k + 1]);

    floatx4 acc[4] = {{0.f, 0.f, 0.f, 0.f},
                      {0.f, 0.f, 0.f, 0.f},
                      {0.f, 0.f, 0.f, 0.f},
                      {0.f, 0.f, 0.f, 0.f}};
#pragma unroll
    for (int k = 0; k < 4; ++k)
#pragma unroll
      for (int tst = 0; tst < 4; ++tst)
        acc[tst] = __builtin_amdgcn_mfma_f32_16x16x32_bf16(aF[tst][k], bF[k],
                                                           acc[tst], 0, 0, 0);
    // acc[tst][j]: row t = tst*16 + g*4 + j, col s-rel = lane&15.
    // invb for col r is this lane's own invb (it loaded row i*16 + r).
#pragma unroll
    for (int tst = 0; tst < 4; ++tst)
#pragma unroll
      for (int j = 0; j < 4; ++j)
        rmax[tst][j] = fmaxf(rmax[tst][j], acc[tst][j] * invb);
  }

  // Butterfly-max over cols (lane bits 0-3) -> per-t max over wave's s-range.
#pragma unroll
  for (int tst = 0; tst < 4; ++tst)
#pragma unroll
    for (int j = 0; j < 4; ++j) {
      float m = rmax[tst][j];
      m = fmaxf(m, __shfl_xor(m, 1));
      m = fmaxf(m, __shfl_xor(m, 2));
      m = fmaxf(m, __shfl_xor(m, 4));
      m = fmaxf(m, __shfl_xor(m, 8));
      rmax[tst][j] = m;  // t = tst*16 + g*4 + j, uniform over lane bits 0-3
    }
  if (r == 0) {
#pragma unroll
    for (int tst = 0; tst < 4; ++tst)
#pragma unroll
      for (int j = 0; j < 4; ++j)
        sPart[wid][tst * 16 + g * 4 + j] = rmax[tst][j];
  }
  __syncthreads();
  // Per-t partial max over this block's 256 s-rows, scaled by invA (positive,
  // commutes with the cross-block max done in the hinge stage).
  if (tid < 64) {
    float m = fmaxf(fmaxf(sPart[0][tid], sPart[1][tid]),
                    fmaxf(sPart[2][tid], sPart[3][tid]));
    part[(size_t)bs2 * 64 + tid] = m * sInvA[tid];
  }
}

// Stage 2: one 1-wave block per batch. part segments for batch b:
// [b*4+0]=pos/h0, [b*4+1]=pos/h1, [b*4+2]=neg/h0, [b*4+3]=neg/h1 (64 t each).
__global__ void hinge_batch_kernel(const float* __restrict__ part,
                                   float* __restrict__ hb) {
  int b = blockIdx.x;       // 0..255
  int t = threadIdx.x;      // 0..63
  const float* p = part + (size_t)b * 256;
  float pm = fmaxf(p[t], p[64 + t]);
  float nm = fmaxf(p[128 + t], p[192 + t]);
#pragma unroll
  for (int m = 1; m < 64; m <<= 1) {
    pm += __shfl_xor(pm, m);
    nm += __shfl_xor(nm, m);
  }
  if (t == 0)
    hb[b] = fmaxf(MARGIN_F + nm * (1.0f / 64.0f) - pm * (1.0f / 64.0f), 0.0f);
}

// Stage 3: mean over 256 batches.
__global__ void final_kernel(const float* __restrict__ hb,
                             float* __restrict__ out) {
  int tid = threadIdx.x;  // 0..255
  float h = hb[tid];
#pragma unroll
  for (int m = 1; m < 64; m <<= 1) h += __shfl_xor(h, m);
  __shared__ float sw[4];
  if ((tid & 63) == 0) sw[tid >> 6] = h;
  __syncthreads();
  if (tid == 0) out[0] = (sw[0] + sw[1] + sw[2] + sw[3]) * (1.0f / 256.0f);
}

extern "C" void kernel_launch(void* const* d_in, const int* in_sizes, int n_in,
                              void* d_out, int out_size, void* d_ws,
                              size_t ws_size, hipStream_t stream) {
  const float* anchor = (const float*)d_in[0];
  const float* pos = (const float*)d_in[1];
  const float* neg = (const float*)d_in[2];
  float* part = (float*)d_ws;               // 1024 x 64 floats = 256 KB
  float* hb = part + 1024 * 64;             // 256 floats
  maxsim_kernel<<<dim3(1024), dim3(256), 0, stream>>>(anchor, pos, neg, part);
  hinge_batch_kernel<<<dim3(256), dim3(64), 0, stream>>>(part, hb);
  final_kernel<<<dim3(1), dim3(256), 0, stream>>>(hb, (float*)d_out);
}

// Round 10
// 41.584 us; speedup vs baseline: 3.4964x; 1.0341x over previous
//
#include <hip/hip_runtime.h>
#include <stdint.h>

// MaxSimLoss: anchor [256,64,128] f32, pos/neg [256,512,128] f32 -> scalar f32.
// R9 post-mortem: three different structures all pin at ~35us (~4 TB/s input);
// occupancy is not the lever. Remaining delta vs the 6.3 TB/s copy ubench:
// fragment-layout global loads scatter 64x16B segments across 16 rows per
// instruction. R10: wave-private double-buffered LDS staging via
// global_load_lds (fully coalesced 1KB/instr, pre-swizzled source), XOR-
// swizzled ds_read_b128 fragment reads, NO barriers in the main loop,
// vmcnt(8) depth-1 pipeline. Numerics identical to R9 (absmax 0.0).

#define MARGIN_F 0.1f

typedef __attribute__((ext_vector_type(8))) short short8;   // 8 bf16
typedef __attribute__((ext_vector_type(4))) float floatx4;  // 4 f32 acc

// f32 -> bf16 round-to-nearest-even (inputs finite).
__device__ __forceinline__ unsigned short f2bf(float f) {
  union { float f; uint32_t u; } x; x.f = f;
  uint32_t u = x.u;
  return (unsigned short)((u + 0x7FFFu + ((u >> 16) & 1u)) >> 16);
}

__device__ __forceinline__ short8 pack8(float4 a, float4 b) {
  short8 r;
  r[0] = (short)f2bf(a.x); r[1] = (short)f2bf(a.y);
  r[2] = (short)f2bf(a.z); r[3] = (short)f2bf(a.w);
  r[4] = (short)f2bf(b.x); r[5] = (short)f2bf(b.y);
  r[6] = (short)f2bf(b.z); r[7] = (short)f2bf(b.w);
  return r;
}

__device__ __forceinline__ float sq4(float4 a) {
  return a.x * a.x + a.y * a.y + a.z * a.z + a.w * a.w;
}

// One block per (batch, side, s-half); 4 waves partition the 256-row s-half
// (64 rows each = 4 chunks of 16 rows = 4 x 8KB). Fragment pattern (verified
// R2/R3): lane holds row (lane&15), elements (lane>>4)*8 + k*32..+8 per
// k-slice; identical for A and B -> D = A.B^T, row(t)=(lane>>4)*4+j,
// col(s)=lane&15.
__global__ __launch_bounds__(256, 2) void maxsim_kernel(
    const float* __restrict__ anchor, const float* __restrict__ pos,
    const float* __restrict__ neg, float* __restrict__ part) {
  __shared__ float sInvA[64];
  __shared__ float sPart[4][64];
  // Wave-private staging: [wave][dbuf][16 rows x 512 B]. 64 KB total.
  __shared__ alignas(16) char sStage[4][2][8192];

  int bs2 = blockIdx.x;     // 0..1023 = ((b*2+side)*2+sh)
  int sh = bs2 & 1;         // s-half
  int bs = bs2 >> 1;        // (batch, side)
  int b = bs >> 1;
  int side = bs & 1;
  const float* base =
      (side ? neg : pos) + (size_t)b * 512 * 128 + (size_t)sh * 256 * 128;
  const float* abase = anchor + (size_t)b * 64 * 128;

  int tid = threadIdx.x;
  int lane = tid & 63;
  int wid = tid >> 6;  // 0..3
  int r = lane & 15;   // fragment row within subtile / accumulator col
  int g = lane >> 4;   // k-group (elements g*8 + k*32)

  const char* sbaseB =
      (const char*)(base + (size_t)wid * 64 * 128);  // wave's 32 KB span

  // Per-lane source offsets for the 8 staging loads of one 8-KB chunk.
  // Instr j covers bytes [j*1024, j*1024+1024). LDS dest is linear
  // (base + lane*16); the source is pre-swizzled with the SAME involution
  // used on the read side (rule #21): f(row) = (row&7)<<4, row = off>>9.
  int l16 = lane * 16;
  int rp = lane >> 5;  // row parity within a 1-KB span
  int srcoff[8];
#pragma unroll
  for (int j = 0; j < 8; ++j)
    srcoff[j] = j * 1024 + (l16 ^ ((((2 * j + rp) & 7)) << 4));

#define STAGE(bufsel, ci)                                                     \
  do {                                                                        \
    const char* cb_ = sbaseB + (ci) * 8192;                                   \
    char* lb_ = &sStage[wid][bufsel][0];                                      \
    _Pragma("unroll") for (int j_ = 0; j_ < 8; ++j_)                          \
        __builtin_amdgcn_global_load_lds(                                     \
            (const __attribute__((address_space(1))) uint32_t*)(cb_ +         \
                                                                srcoff[j_]), \
            (__attribute__((address_space(3))) uint32_t*)(lb_ + j_ * 1024),   \
            16, 0, 0);                                                        \
  } while (0)

  // Stage chunk 0 first so its latency hides under the anchor phase.
  STAGE(0, 0);

  // --- A: all 4 t-subtiles into registers, norms in-register (direct
  // scattered loads; small, once per block). ---
  short8 aF[4][4];
#pragma unroll
  for (int tst = 0; tst < 4; ++tst) {
    const float* arow = abase + (size_t)(tst * 16 + r) * 128 + g * 8;
    float ssa[4];
#pragma unroll
    for (int k = 0; k < 4; ++k) {
      float4 v0 = *reinterpret_cast<const float4*>(arow + k * 32);
      float4 v1 = *reinterpret_cast<const float4*>(arow + k * 32 + 4);
      ssa[k] = sq4(v0) + sq4(v1);
      aF[tst][k] = pack8(v0, v1);
    }
    float ss = (ssa[0] + ssa[1]) + (ssa[2] + ssa[3]);
    ss += __shfl_xor(ss, 16);
    ss += __shfl_xor(ss, 32);
    if (g == 0) sInvA[tst * 16 + r] = 1.0f / fmaxf(sqrtf(ss), 1e-12f);
  }
  __syncthreads();  // sInvA ready; no barriers in the main loop below

  float rmax[4][4];
#pragma unroll
  for (int tst = 0; tst < 4; ++tst)
#pragma unroll
    for (int j = 0; j < 4; ++j) rmax[tst][j] = -1e30f;

  // Fragment read of a staged chunk: same XOR involution as the source.
  int xsw = (r & 7) << 4;
  int rowoff = r * 512;

#define PROCESS(bufsel)                                                     \
  do {                                                                      \
    const char* lb_ = &sStage[wid][bufsel][0];                              \
    float4 v_[8];                                                           \
    _Pragma("unroll") for (int k_ = 0; k_ < 4; ++k_) {                      \
      v_[2 * k_] = *reinterpret_cast<const float4*>(                        \
          lb_ + ((rowoff + g * 32 + k_ * 128) ^ xsw));                      \
      v_[2 * k_ + 1] = *reinterpret_cast<const float4*>(                    \
          lb_ + ((rowoff + g * 32 + k_ * 128 + 16) ^ xsw));                 \
    }                                                                       \
    float ss_ = ((sq4(v_[0]) + sq4(v_[1])) + (sq4(v_[2]) + sq4(v_[3]))) +   \
                ((sq4(v_[4]) + sq4(v_[5])) + (sq4(v_[6]) + sq4(v_[7])));    \
    ss_ += __shfl_xor(ss_, 16);                                             \
    ss_ += __shfl_xor(ss_, 32);                                             \
    float invb_ = 1.0f / fmaxf(sqrtf(ss_), 1e-12f);                         \
    short8 bF_[4];                                                          \
    _Pragma("unroll") for (int k_ = 0; k_ < 4; ++k_) bF_[k_] =              \
        pack8(v_[2 * k_], v_[2 * k_ + 1]);                                  \
    floatx4 acc_[4] = {{0.f, 0.f, 0.f, 0.f},                                \
                       {0.f, 0.f, 0.f, 0.f},                                \
                       {0.f, 0.f, 0.f, 0.f},                                \
                       {0.f, 0.f, 0.f, 0.f}};                               \
    _Pragma("unroll") for (int k_ = 0; k_ < 4; ++k_)                        \
        _Pragma("unroll") for (int t_ = 0; t_ < 4; ++t_) acc_[t_] =         \
            __builtin_amdgcn_mfma_f32_16x16x32_bf16(aF[t_][k_], bF_[k_],    \
                                                    acc_[t_], 0, 0, 0);     \
    _Pragma("unroll") for (int t_ = 0; t_ < 4; ++t_)                        \
        _Pragma("unroll") for (int j_ = 0; j_ < 4; ++j_) rmax[t_][j_] =     \
            fmaxf(rmax[t_][j_], acc_[t_][j_] * invb_);                      \
  } while (0)

  // Main loop, manually unrolled (literal vmcnt immediates). Per iteration:
  // lgkm guard (prior chunk's ds_reads drained before overwriting its buf),
  // stage next chunk, wait current chunk's DMA (vmcnt 8 = next in flight),
  // process current. Wave-private -> no __syncthreads.
  asm volatile("s_waitcnt lgkmcnt(0)" ::: "memory");
  STAGE(1, 1);
  asm volatile("s_waitcnt vmcnt(8)" ::: "memory");
  __builtin_amdgcn_sched_barrier(0);
  PROCESS(0);

  asm volatile("s_waitcnt lgkmcnt(0)" ::: "memory");
  STAGE(0, 2);
  asm volatile("s_waitcnt vmcnt(8)" ::: "memory");
  __builtin_amdgcn_sched_barrier(0);
  PROCESS(1);

  asm volatile("s_waitcnt lgkmcnt(0)" ::: "memory");
  STAGE(1, 3);
  asm volatile("s_waitcnt vmcnt(8)" ::: "memory");
  __builtin_amdgcn_sched_barrier(0);
  PROCESS(0);

  asm volatile("s_waitcnt vmcnt(0)" ::: "memory");
  __builtin_amdgcn_sched_barrier(0);
  PROCESS(1);

  // Butterfly-max over cols (lane bits 0-3) -> per-t max over wave's s-range.
#pragma unroll
  for (int tst = 0; tst < 4; ++tst)
#pragma unroll
    for (int j = 0; j < 4; ++j) {
      float m = rmax[tst][j];
      m = fmaxf(m, __shfl_xor(m, 1));
      m = fmaxf(m, __shfl_xor(m, 2));
      m = fmaxf(m, __shfl_xor(m, 4));
      m = fmaxf(m, __shfl_xor(m, 8));
      rmax[tst][j] = m;  // t = tst*16 + g*4 + j, uniform over lane bits 0-3
    }
  if (r == 0) {
#pragma unroll
    for (int tst = 0; tst < 4; ++tst)
#pragma unroll
      for (int j = 0; j < 4; ++j)
        sPart[wid][tst * 16 + g * 4 + j] = rmax[tst][j];
  }
  __syncthreads();
  // Per-t partial max over this block's 256 s-rows, scaled by invA (positive,
  // commutes with the cross-block max done in the hinge stage).
  if (tid < 64) {
    float m = fmaxf(fmaxf(sPart[0][tid], sPart[1][tid]),
                    fmaxf(sPart[2][tid], sPart[3][tid]));
    part[(size_t)bs2 * 64 + tid] = m * sInvA[tid];
  }
#undef STAGE
#undef PROCESS
}

// Stage 2: one 1-wave block per batch. part segments for batch b:
// [b*4+0]=pos/h0, [b*4+1]=pos/h1, [b*4+2]=neg/h0, [b*4+3]=neg/h1 (64 t each).
__global__ void hinge_batch_kernel(const float* __restrict__ part,
                                   float* __restrict__ hb) {
  int b = blockIdx.x;       // 0..255
  int t = threadIdx.x;      // 0..63
  const float* p = part + (size_t)b * 256;
  float pm = fmaxf(p[t], p[64 + t]);
  float nm = fmaxf(p[128 + t], p[192 + t]);
#pragma unroll
  for (int m = 1; m < 64; m <<= 1) {
    pm += __shfl_xor(pm, m);
    nm += __shfl_xor(nm, m);
  }
  if (t == 0)
    hb[b] = fmaxf(MARGIN_F + nm * (1.0f / 64.0f) - pm * (1.0f / 64.0f), 0.0f);
}

// Stage 3: mean over 256 batches.
__global__ void final_kernel(const float* __restrict__ hb,
                             float* __restrict__ out) {
  int tid = threadIdx.x;  // 0..255
  float h = hb[tid];
#pragma unroll
  for (int m = 1; m < 64; m <<= 1) h += __shfl_xor(h, m);
  __shared__ float sw[4];
  if ((tid & 63) == 0) sw[tid >> 6] = h;
  __syncthreads();
  if (tid == 0) out[0] = (sw[0] + sw[1] + sw[2] + sw[3]) * (1.0f / 256.0f);
}

extern "C" void kernel_launch(void* const* d_in, const int* in_sizes, int n_in,
                              void* d_out, int out_size, void* d_ws,
                              size_t ws_size, hipStream_t stream) {
  const float* anchor = (const float*)d_in[0];
  const float* pos = (const float*)d_in[1];
  const float* neg = (const float*)d_in[2];
  float* part = (float*)d_ws;               // 1024 x 64 floats = 256 KB
  float* hb = part + 1024 * 64;             // 256 floats
  maxsim_kernel<<<dim3(1024), dim3(256), 0, stream>>>(anchor, pos, neg, part);
  hinge_batch_kernel<<<dim3(256), dim3(64), 0, stream>>>(part, hb);
  final_kernel<<<dim3(1), dim3(256), 0, stream>>>(hb, (float*)d_out);
}